// Round 8
// baseline (97.751 us; speedup 1.0000x reference)
//
#include <hip/hip_runtime.h>

// Problem constants (match reference)
#define BB 32
#define SS 64
#define TT 512
#define VV 50257
#define DD 128

#define DSLICES 4
#define DW (DD / DSLICES)        // 32 dims per block -> 128 B = full cache line per row slice
#define NCH 32                   // chunk groups per block
#define CHL (TT / NCH)           // 16 tokens per chunk
#define NTHREADS (NCH * DW)      // 1024
#define NSLOT 130                // >= 129 max distinct span boundaries
#define NWORDS 17                // ceil(513/32) boundary flag words
#define HSIZE 2048               // dup-filter hash buckets per table (8 KB each)
#define MAXDUP 512               // >= max dups per row (511)

// One block per (row b, 32-dim slice). Single gather pass; boundary-compacted
// prefix table PB in LDS; dup detect via DOUBLE hash gate (E[scanners] ~ 13/row)
// + forward int4 scan (independent pipelineable LDS reads). 4 barriers total.
// out[b,s,d] = PB[slot[j]] - PB[slot[i]] + bias - sum of in-span dup W rows.
__global__ __launch_bounds__(NTHREADS) void fused_bow(
    const int* __restrict__ tok,     // (B,T)
    const int* __restrict__ spans,   // (B,S,2)
    const float* __restrict__ W,     // (V,D)
    const float* __restrict__ bias,  // (D)
    float* __restrict__ out)         // (B,S,D)
{
    const int b     = blockIdx.x >> 2;
    const int dbase = (blockIdx.x & 3) * DW;
    const int tid   = threadIdx.x;
    const int c     = tid >> 5;        // chunk group 0..31
    const int d     = tid & (DW - 1);  // dim 0..31

    __shared__ alignas(16) int tokS[TT];          // 2 KB
    __shared__ int spanI[SS], spanJ[SS];          // 512 B
    __shared__ unsigned int words[NWORDS];        // 68 B boundary bitmask
    __shared__ short slot[TT + 1];                // 1 KB exclusive flag-prefix
    __shared__ float csum[NCH][DW];               // 4 KB chunk sums
    __shared__ unsigned int hash1[HSIZE];         // 8 KB dup filter A
    __shared__ unsigned int hash2[HSIZE];         // 8 KB dup filter B (independent)
    __shared__ int dupT[MAXDUP], dupP[MAXDUP], dupV[MAXDUP];  // 6 KB
    __shared__ int ndup;
    __shared__ float PB[NSLOT][DW];               // 16.6 KB boundary prefixes

    // ---- P0: stage + init ----
    if (tid < TT) tokS[tid] = tok[b * TT + tid];
    if (tid < SS) {
        spanI[tid] = spans[(b * SS + tid) * 2 + 0];
        spanJ[tid] = spans[(b * SS + tid) * 2 + 1];
    }
    if (tid < NWORDS) words[tid] = 0u;
    if (tid == 0) ndup = 0;
    for (int h = tid; h < HSIZE; h += NTHREADS) {
        hash1[h] = 0xFFFFFFFFu;
        hash2[h] = 0xFFFFFFFFu;
    }
    __syncthreads();

    // ---- P1: boundary bits; two hash passes (min position per bucket) ----
    if (tid < SS) {
        const int i = spanI[tid], j = spanJ[tid];
        atomicOr(&words[i >> 5], 1u << (i & 31));
        atomicOr(&words[j >> 5], 1u << (j & 31));
    }
    if (tid < TT) {
        const unsigned int v = (unsigned int)tokS[tid];
        atomicMin(&hash1[(v * 2654435761u) >> 21], (unsigned int)tid);
        atomicMin(&hash2[(v * 0x85EBCA6Bu) >> 21], (unsigned int)tid);
    }
    __syncthreads();

    // ---- P2: slot via popcount; double-gated dup detect (forward scan, no break);
    //          single gather pass with register chunk-prefixes ----
    if (tid <= TT) {
        const int wt = tid >> 5;
        int s = 0;
        for (int w = 0; w < wt; ++w) s += __popc(words[w]);
        s += __popc(words[wt] & ((1u << (tid & 31)) - 1u));
        slot[tid] = (short)s;
    }
    if (tid < TT) {
        const unsigned int v = (unsigned int)tokS[tid];
        // true dup always passes both gates (its real prev sits in both buckets);
        // false positives must collide in BOTH tables: E ~ (t/2048)^2
        if (hash1[(v * 2654435761u) >> 21] < (unsigned int)tid &&
            hash2[(v * 0x85EBCA6Bu) >> 21] < (unsigned int)tid) {
            const int4* rowv = reinterpret_cast<const int4*>(tokS);
            int p = -1;
            const int n4 = (tid + 3) >> 2;         // int4 blocks covering [0, tid)
            for (int u4 = 0; u4 < n4; ++u4) {
                const int4 q = rowv[u4];           // LAST match = nearest previous
                const int base = u4 << 2;
                if (base + 0 < tid && q.x == (int)v) p = base + 0;
                if (base + 1 < tid && q.y == (int)v) p = base + 1;
                if (base + 2 < tid && q.z == (int)v) p = base + 2;
                if (base + 3 < tid && q.w == (int)v) p = base + 3;
            }
            if (p >= 0) {
                const int k = atomicAdd(&ndup, 1);
                dupT[k] = tid; dupP[k] = p; dupV[k] = (int)v;
            }
        }
    }
    const float* Wd = W + dbase;
    const int tbase = c * CHL;
    float pref[CHL];                               // chunk-local prefixes in regs
    {
        float acc = 0.f;
#pragma unroll
        for (int t = 0; t < CHL; ++t) {
            acc += Wd[(size_t)tokS[tbase + t] * DD + d];
            pref[t] = acc;
        }
        csum[c][d] = acc;
    }
    __syncthreads();

    // ---- P3: chunk offset (register), then boundary PB writes with offset folded ----
    {
        float o = 0.f;
        for (int cc = 0; cc < c; ++cc) o += csum[cc][d];
#pragma unroll
        for (int t = 0; t < CHL; ++t) {
            const int p = tbase + t + 1;
            if ((words[p >> 5] >> (p & 31)) & 1u)
                PB[slot[p]][d] = pref[t] + o;
        }
    }
    if (tid < DW && (words[0] & 1u)) PB[0][tid] = 0.f;  // slot of position 0 is 0
    __syncthreads();

    // ---- P4: span outputs (2 spans per chunk group) ----
    const int nd = ndup;
    const float bv = bias[dbase + d];
    for (int s = c; s < SS; s += NCH) {
        const int i = spanI[s], j = spanJ[s];
        float r = PB[slot[j]][d] - PB[slot[i]][d] + bv;
        for (int k = 0; k < nd; ++k)
            if (dupT[k] < j && dupP[k] >= i)       // in-span duplicate
                r -= Wd[(size_t)dupV[k] * DD + d];
        out[(size_t)(b * SS + s) * DD + dbase + d] = r;
    }
}

extern "C" void kernel_launch(void* const* d_in, const int* in_sizes, int n_in,
                              void* d_out, int out_size, void* d_ws, size_t ws_size,
                              hipStream_t stream) {
    const int*   word_encs = (const int*)  d_in[0];   // (B,T) int32
    const int*   span_idxs = (const int*)  d_in[1];   // (B,S,2) int32
    const float* W         = (const float*)d_in[2];   // (V,D) f32
    const float* bias      = (const float*)d_in[3];   // (D,) f32
    float*       out       = (float*)      d_out;     // (B,S,D) f32

    fused_bow<<<BB * DSLICES, NTHREADS, 0, stream>>>(word_encs, span_idxs, W, bias, out);
}

// Round 9
// 94.062 us; speedup vs baseline: 1.0392x; 1.0392x over previous
//
#include <hip/hip_runtime.h>

// Problem constants (match reference)
#define BB 32
#define SS 64
#define TT 512
#define VV 50257
#define DD 128

#define DSLICES 4
#define DW (DD / DSLICES)        // 32 dims per block -> 128 B = full cache line per row slice
#define NCH 32                   // chunk groups per block
#define CHL (TT / NCH)           // 16 tokens per chunk
#define NTHREADS (NCH * DW)      // 1024
#define NSLOT 130                // >= 129 max distinct span boundaries
#define NWORDS 17                // ceil(513/32) boundary flag words
#define HSIZE 2048               // dup-filter hash buckets (8 KB)
#define MAXDUP 512               // >= max dups per row (511)

// One block per (row b, 32-dim slice). Single gather pass; boundary-compacted
// prefix table PB in LDS; dup list via hash gate + forward int4 scan (no
// dependent-latency chains anywhere). 4 barriers total.
// out[b,s,d] = PB[slot[j]] - PB[slot[i]] + bias - sum of in-span dup W rows.
__global__ __launch_bounds__(NTHREADS) void fused_bow(
    const int* __restrict__ tok,     // (B,T)
    const int* __restrict__ spans,   // (B,S,2)
    const float* __restrict__ W,     // (V,D)
    const float* __restrict__ bias,  // (D)
    float* __restrict__ out)         // (B,S,D)
{
    const int b     = blockIdx.x >> 2;
    const int dbase = (blockIdx.x & 3) * DW;
    const int tid   = threadIdx.x;
    const int c     = tid >> 5;        // chunk group 0..31
    const int d     = tid & (DW - 1);  // dim 0..31

    __shared__ alignas(16) int tokS[TT];          // 2 KB
    __shared__ int spanI[SS], spanJ[SS];          // 512 B
    __shared__ unsigned int words[NWORDS];        // 68 B boundary bitmask
    __shared__ short slot[TT + 1];                // 1 KB exclusive flag-prefix
    __shared__ float csum[NCH][DW];               // 4 KB chunk sums
    __shared__ unsigned int hashT[HSIZE];         // 8 KB dup filter
    __shared__ int dupT[MAXDUP], dupP[MAXDUP], dupV[MAXDUP];  // 6 KB
    __shared__ int ndup;
    __shared__ float PB[NSLOT][DW];               // 16.6 KB boundary prefixes

    // ---- P0: stage + init ----
    if (tid < TT) tokS[tid] = tok[b * TT + tid];
    if (tid < SS) {
        spanI[tid] = spans[(b * SS + tid) * 2 + 0];
        spanJ[tid] = spans[(b * SS + tid) * 2 + 1];
    }
    if (tid < NWORDS) words[tid] = 0u;
    if (tid == 0) ndup = 0;
    for (int h = tid; h < HSIZE; h += NTHREADS) hashT[h] = 0xFFFFFFFFu;
    __syncthreads();

    // ---- P1: boundary bits; hash pass (min position per bucket) ----
    if (tid < SS) {
        const int i = spanI[tid], j = spanJ[tid];
        atomicOr(&words[i >> 5], 1u << (i & 31));
        atomicOr(&words[j >> 5], 1u << (j & 31));
    }
    if (tid < TT) {
        const unsigned int h = ((unsigned int)tokS[tid] * 2654435761u) >> 21;
        atomicMin(&hashT[h], (unsigned int)tid);
    }
    __syncthreads();

    // ---- P2: slot via popcount; gated dup detect (forward scan, no break);
    //          single gather pass with register chunk-prefixes ----
    if (tid <= TT) {
        const int wt = tid >> 5;
        int s = 0;
        for (int w = 0; w < wt; ++w) s += __popc(words[w]);
        s += __popc(words[wt] & ((1u << (tid & 31)) - 1u));
        slot[tid] = (short)s;
    }
    if (tid < TT) {
        const int v = tokS[tid];
        const unsigned int h = ((unsigned int)v * 2654435761u) >> 21;
        if (hashT[h] < (unsigned int)tid) {        // candidate: dup OR hash collision
            // forward int4 scan keeping LAST match -> nearest previous occurrence;
            // independent vector LDS reads, fully pipelineable (no dependent chain)
            const int4* rowv = reinterpret_cast<const int4*>(tokS);
            int p = -1;
            const int n4 = (tid + 3) >> 2;         // int4 blocks covering [0, tid)
            for (int u4 = 0; u4 < n4; ++u4) {
                const int4 q = rowv[u4];
                const int base = u4 << 2;
                if (base + 0 < tid && q.x == v) p = base + 0;
                if (base + 1 < tid && q.y == v) p = base + 1;
                if (base + 2 < tid && q.z == v) p = base + 2;
                if (base + 3 < tid && q.w == v) p = base + 3;
            }
            if (p >= 0) {
                const int k = atomicAdd(&ndup, 1);
                dupT[k] = tid; dupP[k] = p; dupV[k] = v;
            }
        }
    }
    const float* Wd = W + dbase;
    const int tbase = c * CHL;
    float pref[CHL];                               // chunk-local prefixes in regs
    {
        float acc = 0.f;
#pragma unroll
        for (int t = 0; t < CHL; ++t) {
            acc += Wd[(size_t)tokS[tbase + t] * DD + d];
            pref[t] = acc;
        }
        csum[c][d] = acc;
    }
    __syncthreads();

    // ---- P3: chunk offset (register), then boundary PB writes with offset folded ----
    {
        float o = 0.f;
        for (int cc = 0; cc < c; ++cc) o += csum[cc][d];
#pragma unroll
        for (int t = 0; t < CHL; ++t) {
            const int p = tbase + t + 1;
            if ((words[p >> 5] >> (p & 31)) & 1u)
                PB[slot[p]][d] = pref[t] + o;
        }
    }
    if (tid < DW && (words[0] & 1u)) PB[0][tid] = 0.f;  // slot of position 0 is 0
    __syncthreads();

    // ---- P4: span outputs (2 spans per chunk group) ----
    const int nd = ndup;
    const float bv = bias[dbase + d];
    for (int s = c; s < SS; s += NCH) {
        const int i = spanI[s], j = spanJ[s];
        float r = PB[slot[j]][d] - PB[slot[i]][d] + bv;
        for (int k = 0; k < nd; ++k)
            if (dupT[k] < j && dupP[k] >= i)       // in-span duplicate
                r -= Wd[(size_t)dupV[k] * DD + d];
        out[(size_t)(b * SS + s) * DD + dbase + d] = r;
    }
}

extern "C" void kernel_launch(void* const* d_in, const int* in_sizes, int n_in,
                              void* d_out, int out_size, void* d_ws, size_t ws_size,
                              hipStream_t stream) {
    const int*   word_encs = (const int*)  d_in[0];   // (B,T) int32
    const int*   span_idxs = (const int*)  d_in[1];   // (B,S,2) int32
    const float* W         = (const float*)d_in[2];   // (V,D) f32
    const float* bias      = (const float*)d_in[3];   // (D,) f32
    float*       out       = (float*)      d_out;     // (B,S,D) f32

    fused_bow<<<BB * DSLICES, NTHREADS, 0, stream>>>(word_encs, span_idxs, W, bias, out);
}